// Round 1
// 437.412 us; speedup vs baseline: 1.6538x; 1.6538x over previous
//
#include <hip/hip_runtime.h>
#include <stdint.h>

// RNN scan: h_t = tanh(h_{t-1} @ Whh + b_hh + x_t * Wxh + b_xh), out = h_T @ Wout + b_out
// B=16384 rows, T=1024 steps, H=32 hidden.
//
// Round 2: move the h@Whh matmul from the (98%-busy) VALU pipe to the (0%-busy)
// matrix pipe.
//
//  - One wave per 16-row tile (1024 blocks x 64 thr, 1 wave/SIMD, all resident).
//  - fp32 fidelity on matrix cores via 2-term f16 split with 2^11-scaled residual:
//      h = h1 + 2^-11 h2',  W = W1 + 2^-11 W2'   (residuals f16-normal, no denorm flush)
//    products h1W1 (chain A, C=x*Wxh+bias) and h1W2' + h2'W1 (chain B, C=0),
//    recombined as acc = chainA + 2^-11 * chainB. Dropped h2'W2' ~ 2^-22.
//  - Swapped product g^T = W^T * h^T so D keeps batch-row on lane&15, matching the
//    B-operand n-mapping: the per-step j->k redistribution is a tiny wave-synchronous
//    LDS round trip (4 ds_write_b64 + 2 ds_read_b128). Single-wave blocks => NO barriers.
//  - x staged transposed in LDS per 64-step chunk, prefetched one chunk ahead;
//    per-step x read is a broadcast ds_read_b32.
//
// MFMA 16x16x32 f16 layouts (per guide sec.3, m89-verified D mapping):
//   A (= W^T frag): lane l: m = l&15 (j within half), k = 8*(l>>4)+e, e=0..7
//   B (= h^T frag): lane l: n = l&15 (batch row r),  k = 8*(l>>4)+e
//   D:              lane l: n = l&15 (batch row r),  m = 4*(l>>4)+reg (j within half)

typedef _Float16 half8  __attribute__((ext_vector_type(8)));
typedef _Float16 half2v __attribute__((ext_vector_type(2)));
typedef float    f32x4  __attribute__((ext_vector_type(4)));

constexpr int Bsz  = 16384;
constexpr int Tlen = 1024;
constexpr int NTILES = Bsz / 16;          // 1024 blocks, 16 rows each

constexpr float RESCALE     = 2048.0f;     // 2^11
constexpr float INV_RESCALE = 1.0f / 2048.0f;

__device__ __forceinline__ float fast_tanh(float x) {
    // tanh(x) = sign(x) * (1 - e) / (1 + e),  e = exp(-2|x|)  -- no overflow path
    float ax = __builtin_fabsf(x);
    float e  = __builtin_amdgcn_exp2f(ax * -2.8853900817779268f); // exp(-2ax)
    float r  = (1.0f - e) * __builtin_amdgcn_rcpf(1.0f + e);
    return __builtin_copysignf(r, x);
}

__device__ __forceinline__ uint32_t packh2(_Float16 a, _Float16 b) {
    half2v v; v[0] = a; v[1] = b;                 // low16 = a (even k), high16 = b
    return __builtin_bit_cast(uint32_t, v);
}

__global__ __launch_bounds__(64, 1)
void rnn_scan_mfma(const float* __restrict__ x,    // [B,T]
                   const float* __restrict__ Wxh,  // [1,H]
                   const float* __restrict__ b_xh, // [H]
                   const float* __restrict__ Whh,  // [H,H] row-major (i,j)
                   const float* __restrict__ b_hh, // [H]
                   const float* __restrict__ Wout, // [H,1]
                   const float* __restrict__ b_out,// [1]
                   float* __restrict__ out)        // [B,1]
{
    // hterm[term][r][i-pair]: packed f16 pairs (even k in low16). pad 20 words:
    // row stride 80 B keeps ds_read_b128 16B-aligned and spreads banks.
    __shared__ uint32_t hterm[2][16][20];
    // xsh[r][t_local]: pad 68 keeps float4 staging writes 16B-aligned; per-step
    // read xsh[r][t] is a 16-address broadcast (conflict-free).
    __shared__ float xsh[16][68];

    const int lane = threadIdx.x;      // 0..63 (single-wave block)
    const int r16  = lane & 15;
    const int G    = lane >> 4;        // 0..3
    const int tile = blockIdx.x;

    // ---- one-time: A-operand fragments of W^T, 2-term split -------------------
    half8 W1[2], W2[2];                // [half: j<16 / j>=16]
    #pragma unroll
    for (int h = 0; h < 2; ++h) {
        #pragma unroll
        for (int e = 0; e < 8; ++e) {
            float w = Whh[(8 * G + e) * 32 + (r16 + 16 * h)]; // A[m=j][k=i] = W[i][j]
            _Float16 a = (_Float16)w;
            W1[h][e] = a;
            W2[h][e] = (_Float16)((w - (float)a) * RESCALE);
        }
    }

    // per-lane output-j constants: j = 4*G + reg + 16*h, index e = 4*h + reg
    float wxhc[8], bc[8], woutc[8];
    #pragma unroll
    for (int h = 0; h < 2; ++h)
        #pragma unroll
        for (int reg = 0; reg < 4; ++reg) {
            int j = 4 * G + reg + 16 * h;
            wxhc[4 * h + reg]  = Wxh[j];
            bc[4 * h + reg]    = b_hh[j] + b_xh[j];
            woutc[4 * h + reg] = Wout[j];
        }
    const float bout = b_out[0];

    // h0 = 0: each lane owns pairs {2G, 2G+1, 8+2G, 8+2G+1} per term (covers all 16)
    #pragma unroll
    for (int T = 0; T < 2; ++T) {
        *(uint2*)&hterm[T][r16][2 * G]     = make_uint2(0u, 0u);
        *(uint2*)&hterm[T][r16][8 + 2 * G] = make_uint2(0u, 0u);
    }

    const float* xrow = x + (size_t)(tile * 16 + r16) * Tlen;

    // prefetch first x chunk: lane covers t_local = 4G + 16m + {0..3}
    float4 xb0 = *(const float4*)&xrow[4 * G +  0];
    float4 xb1 = *(const float4*)&xrow[4 * G + 16];
    float4 xb2 = *(const float4*)&xrow[4 * G + 32];
    float4 xb3 = *(const float4*)&xrow[4 * G + 48];

    const f32x4 zero4 = {0.0f, 0.0f, 0.0f, 0.0f};
    float t8[8] = {0.f, 0.f, 0.f, 0.f, 0.f, 0.f, 0.f, 0.f};

    #pragma unroll 1
    for (int tc = 0; tc < Tlen; tc += 64) {
        // commit prefetched chunk (transposed) -- wave-synchronous, no barrier
        *(float4*)&xsh[r16][4 * G +  0] = xb0;
        *(float4*)&xsh[r16][4 * G + 16] = xb1;
        *(float4*)&xsh[r16][4 * G + 32] = xb2;
        *(float4*)&xsh[r16][4 * G + 48] = xb3;
        if (tc + 64 < Tlen) {
            xb0 = *(const float4*)&xrow[tc + 64 + 4 * G +  0];
            xb1 = *(const float4*)&xrow[tc + 64 + 4 * G + 16];
            xb2 = *(const float4*)&xrow[tc + 64 + 4 * G + 32];
            xb3 = *(const float4*)&xrow[tc + 64 + 4 * G + 48];
        }

        #pragma unroll 1
        for (int tl = 0; tl < 64; ++tl) {
            // B-fragments: previous h, both terms. k-pairs 4G..4G+3 of row r16.
            half8 hb1 = __builtin_bit_cast(half8, *(const uint4*)&hterm[0][r16][4 * G]);
            half8 hb2 = __builtin_bit_cast(half8, *(const uint4*)&hterm[1][r16][4 * G]);
            float xv  = xsh[r16][tl];                       // broadcast read

            // chain A C-init: x_t * Wxh[j] + (b_hh[j] + b_xh[j]) in D layout
            f32x4 c0, c1;
            #pragma unroll
            for (int reg = 0; reg < 4; ++reg) {
                c0[reg] = __builtin_fmaf(xv, wxhc[reg],     bc[reg]);
                c1[reg] = __builtin_fmaf(xv, wxhc[4 + reg], bc[4 + reg]);
            }

            // chain A: h1*W1 (scale 1);  chain B: h2'*W1 + h1*W2' (scale 2^-11)
            f32x4 a0 = __builtin_amdgcn_mfma_f32_16x16x32_f16(W1[0], hb1, c0,    0, 0, 0);
            f32x4 a1 = __builtin_amdgcn_mfma_f32_16x16x32_f16(W1[1], hb1, c1,    0, 0, 0);
            f32x4 e0 = __builtin_amdgcn_mfma_f32_16x16x32_f16(W1[0], hb2, zero4, 0, 0, 0);
            f32x4 e1 = __builtin_amdgcn_mfma_f32_16x16x32_f16(W1[1], hb2, zero4, 0, 0, 0);
            e0 = __builtin_amdgcn_mfma_f32_16x16x32_f16(W2[0], hb1, e0, 0, 0, 0);
            e1 = __builtin_amdgcn_mfma_f32_16x16x32_f16(W2[1], hb1, e1, 0, 0, 0);

            #pragma unroll
            for (int reg = 0; reg < 4; ++reg) {
                t8[reg]     = fast_tanh(__builtin_fmaf(e0[reg], INV_RESCALE, a0[reg]));
                t8[4 + reg] = fast_tanh(__builtin_fmaf(e1[reg], INV_RESCALE, a1[reg]));
            }

            // split to 2-term f16 + publish. Lane's j-quad (4G..4G+3)+16h -> pairs
            // (2G+8h, 2G+8h+1); adjacent words -> one ds_write_b64 per term per half.
            #pragma unroll
            for (int h = 0; h < 2; ++h) {
                float v0 = t8[4 * h + 0], v1 = t8[4 * h + 1];
                float v2 = t8[4 * h + 2], v3 = t8[4 * h + 3];
                _Float16 p0 = (_Float16)v0, p1 = (_Float16)v1;
                _Float16 p2 = (_Float16)v2, p3 = (_Float16)v3;
                float r0 = (v0 - (float)p0) * RESCALE, r1 = (v1 - (float)p1) * RESCALE;
                float r2 = (v2 - (float)p2) * RESCALE, r3 = (v3 - (float)p3) * RESCALE;
                *(uint2*)&hterm[0][r16][2 * G + 8 * h] =
                    make_uint2(packh2(p0, p1), packh2(p2, p3));
                *(uint2*)&hterm[1][r16][2 * G + 8 * h] =
                    make_uint2(packh2((_Float16)r0, (_Float16)r1),
                               packh2((_Float16)r2, (_Float16)r3));
            }
        }
    }

    // out[row] = sum_j h_T[row][j] * Wout[j] + b_out
    float v = 0.0f;
    #pragma unroll
    for (int e = 0; e < 8; ++e) v = __builtin_fmaf(t8[e], woutc[e], v);
    v += __shfl_xor(v, 16, 64);   // fold G^1
    v += __shfl_xor(v, 32, 64);   // fold G^2
    if (G == 0) out[tile * 16 + r16] = v + bout;
}

extern "C" void kernel_launch(void* const* d_in, const int* in_sizes, int n_in,
                              void* d_out, int out_size, void* d_ws, size_t ws_size,
                              hipStream_t stream) {
    const float* x     = (const float*)d_in[0];
    const float* Wxh   = (const float*)d_in[1];
    const float* b_xh  = (const float*)d_in[2];
    const float* Whh   = (const float*)d_in[3];
    const float* b_hh  = (const float*)d_in[4];
    const float* Wout  = (const float*)d_in[5];
    const float* b_out = (const float*)d_in[6];
    float* outp = (float*)d_out;

    rnn_scan_mfma<<<NTILES, 64, 0, stream>>>(x, Wxh, b_xh, Whh, b_hh, Wout,
                                             b_out, outp);
}